// Round 10
// baseline (175.692 us; speedup 1.0000x reference)
//
#include <hip/hip_runtime.h>

#define N_NODES 50000
#define N_EDGES 800000
#define IN_DIM 256
#define HID 64
#define HEADS 4
#define NFEAT 256   /* HEADS*HID */
#define N_CLASSES 40
#define NC_PAD 48
#define NEG_SLOPE 0.2f
#define BIN_CAP 64  /* max in-degree; Poisson(16) -> P(>=64) ~ 1e-18 */

typedef __attribute__((ext_vector_type(8))) short short8;
typedef __attribute__((ext_vector_type(4))) float f32x4;

__device__ __forceinline__ unsigned short f2bf(float x) {
    unsigned u = __float_as_uint(x);
    unsigned r = u + 0x7FFFu + ((u >> 16) & 1u);   // round-to-nearest-even
    return (unsigned short)(r >> 16);
}
__device__ __forceinline__ float bf_lo(unsigned u) {
    return __uint_as_float(u << 16);
}
__device__ __forceinline__ float bf_hi(unsigned u) {
    return __uint_as_float(u & 0xFFFF0000u);
}

// ---------------------------------------------------------------------------
// Pack W0 [256][256] and fc_W [256][40->48] into MFMA B-frag bf16 layouts.
// Also zeroes cnt[] (replaces a memset dispatch).
__global__ __launch_bounds__(256) void pack_weights(
    const float* __restrict__ W0, unsigned short* __restrict__ Wf,
    const float* __restrict__ W2, unsigned short* __restrict__ Wf2,
    int* __restrict__ cnt)
{
    int t = blockIdx.x * 256 + threadIdx.x;
    if (t < N_NODES) cnt[t] = 0;
    if (t < 65536) {
        int c = t & 255;
        int k = t >> 8;
        int kb = k >> 5, r = k & 31;
        int g = r >> 3, e = r & 7;
        Wf[((size_t)(kb * 256 + c) * 4 + g) * 8 + e] = f2bf(W0[(size_t)k * 256 + c]);
    } else {
        int t2 = t - 65536;
        if (t2 >= 8 * NC_PAD * 32) return;
        int c = (t2 >> 5) % NC_PAD;
        int kb = t2 / (NC_PAD * 32);
        int r = t2 & 31;
        int g = r >> 3, e = r & 7;
        int k = kb * 32 + g * 8 + e;
        float v = (c < N_CLASSES) ? W2[(size_t)k * N_CLASSES + c] : 0.f;
        Wf2[((size_t)(kb * NC_PAD + c) * 4 + g) * 8 + e] = f2bf(v);
    }
}

// ---------------------------------------------------------------------------
// Projection via MFMA bf16, direct-register A-frags (no LDS, no barriers),
// fused el/er epilogue, bf16 h output.
__global__ __launch_bounds__(256) void proj_mfma(
    const float* __restrict__ feat, const unsigned short* __restrict__ Wf,
    const float* __restrict__ al, const float* __restrict__ ar,
    unsigned short* __restrict__ hb16, float* __restrict__ el, float* __restrict__ er)
{
    const int tid  = threadIdx.x;
    const int lane = tid & 63;
    const int w    = tid >> 6;
    const int c    = lane & 15;
    const int g    = lane >> 4;
    const int row0 = blockIdx.x * 64;

    float alv[16], arv[16];
    #pragma unroll
    for (int f = 0; f < 16; ++f) { alv[f] = al[f * 16 + c]; arv[f] = ar[f * 16 + c]; }

    f32x4 acc[16];
    #pragma unroll
    for (int f = 0; f < 16; ++f) acc[f] = (f32x4){0.f, 0.f, 0.f, 0.f};

    const int arow = min(row0 + w * 16 + c, N_NODES - 1);
    const float* ap = &feat[(size_t)arow * IN_DIM + g * 8];

    for (int kb = 0; kb < 8; ++kb) {
        float4 v0 = *reinterpret_cast<const float4*>(ap + kb * 32);
        float4 v1 = *reinterpret_cast<const float4*>(ap + kb * 32 + 4);
        unsigned short us[8];
        us[0]=f2bf(v0.x); us[1]=f2bf(v0.y); us[2]=f2bf(v0.z); us[3]=f2bf(v0.w);
        us[4]=f2bf(v1.x); us[5]=f2bf(v1.y); us[6]=f2bf(v1.z); us[7]=f2bf(v1.w);
        short8 av = *reinterpret_cast<short8*>(us);
        #pragma unroll
        for (int f = 0; f < 16; ++f) {
            short8 bv = *reinterpret_cast<const short8*>(
                &Wf[((size_t)(kb * 256 + f * 16 + c) * 4 + g) * 8]);
            acc[f] = __builtin_amdgcn_mfma_f32_16x16x32_bf16(av, bv, acc[f], 0, 0, 0);
        }
    }

    const int baserow = row0 + w * 16 + g * 4;
    #pragma unroll
    for (int reg = 0; reg < 4; ++reg) {
        int grow = baserow + reg;
        bool ok = grow < N_NODES;
        float pl[4] = {0.f,0.f,0.f,0.f}, pr[4] = {0.f,0.f,0.f,0.f};
        #pragma unroll
        for (int f = 0; f < 16; ++f) {
            float v = acc[f][reg];
            pl[f >> 2] += v * alv[f];
            pr[f >> 2] += v * arv[f];
            if (ok) hb16[(size_t)grow * NFEAT + f * 16 + c] = f2bf(v);
        }
        #pragma unroll
        for (int hh = 0; hh < 4; ++hh) {
            #pragma unroll
            for (int off = 8; off; off >>= 1) {
                pl[hh] += __shfl_xor(pl[hh], off);
                pr[hh] += __shfl_xor(pr[hh], off);
            }
        }
        if (ok && c == 0) {
            #pragma unroll
            for (int hh = 0; hh < 4; ++hh) {
                el[grow * 4 + hh] = pl[hh];
                er[grow * 4 + hh] = pr[hh];
            }
        }
    }
}

// ---------------------------------------------------------------------------
// FC via MFMA bf16, direct-register A-frags.
__global__ __launch_bounds__(256) void fc_mfma(
    const unsigned short* __restrict__ aggb, const unsigned short* __restrict__ Wf2,
    const float* __restrict__ bias, float* __restrict__ out)
{
    const int tid  = threadIdx.x;
    const int lane = tid & 63;
    const int w    = tid >> 6;
    const int c    = lane & 15;
    const int g    = lane >> 4;
    const int row0 = blockIdx.x * 64;

    f32x4 acc[3];
    #pragma unroll
    for (int f = 0; f < 3; ++f) acc[f] = (f32x4){0.f, 0.f, 0.f, 0.f};

    const int arow = min(row0 + w * 16 + c, N_NODES - 1);
    const unsigned short* ap = &aggb[(size_t)arow * NFEAT + g * 8];

    for (int kb = 0; kb < 8; ++kb) {
        short8 av = *reinterpret_cast<const short8*>(ap + kb * 32);
        #pragma unroll
        for (int f = 0; f < 3; ++f) {
            short8 bv = *reinterpret_cast<const short8*>(
                &Wf2[((size_t)(kb * NC_PAD + f * 16 + c) * 4 + g) * 8]);
            acc[f] = __builtin_amdgcn_mfma_f32_16x16x32_bf16(av, bv, acc[f], 0, 0, 0);
        }
    }

    const int baserow = row0 + w * 16 + g * 4;
    #pragma unroll
    for (int reg = 0; reg < 4; ++reg) {
        int grow = baserow + reg;
        if (grow >= N_NODES) continue;
        #pragma unroll
        for (int f = 0; f < 3; ++f) {
            int col = f * 16 + c;
            if (col < N_CLASSES)
                out[(size_t)grow * N_CLASSES + col] = acc[f][reg] + bias[col];
        }
    }
}

// ---------------------------------------------------------------------------
// Slim binned scatter: src index only (4 B per edge). No el/er reads, no exp
// (moved to gat_agg where each lane computes only its own head's logit).
__global__ __launch_bounds__(256) void scatter_bins(
    const int* __restrict__ src, const int* __restrict__ dst,
    int* __restrict__ cnt, int* __restrict__ bins_src)
{
    int e = blockIdx.x * 256 + threadIdx.x;
    if (e >= N_EDGES) return;
    int d = dst[e];
    int pos = atomicAdd(&cnt[d], 1);
    if (pos >= BIN_CAP) return;   // impossible for this input (P ~ 1e-18)
    bins_src[(d << 6) + pos] = src[e];
}

// ---------------------------------------------------------------------------
// Fused aggregation with inline logits. One wave per node, all 4 heads.
// Lane l: feature-uint4 slot hlane=l&31 (head=hlane>>3), edge parity
// ehalf=l>>5. Per iteration: 4 B src load (half-wave uniform, L1),
// 4 B el gather for THIS lane's head (el = 800 KB, L2-hot), ~6 VALU
// (add+leaky+exp), one dwordx4 feature gather, 8 fma. Deferred
// normalization; halves combined at the end.
__global__ __launch_bounds__(256) void gat_agg_kernel(
    const int* __restrict__ cnt, const int* __restrict__ bins_src,
    const float* __restrict__ el, const float* __restrict__ er,
    const uint4* __restrict__ hb4, uint4* __restrict__ aggb4)
{
    const int lane  = threadIdx.x & 63;
    const int w     = threadIdx.x >> 6;
    const int d     = blockIdx.x * 4 + w;
    const int hlane = lane & 31;
    const int head  = hlane >> 3;
    const int ehalf = lane >> 5;

    if (d >= N_NODES) return;
    const int deg = min(cnt[d], BIN_CAP);
    const float er_h = er[(d << 2) + head];

    float acc[8] = {0.f,0.f,0.f,0.f,0.f,0.f,0.f,0.f};
    float sm = 0.f;
    const uint4* hp = hb4 + hlane;
    const int*   bp = bins_src + (d << 6);

    #pragma unroll 4
    for (int jj = 0; jj < deg; jj += 2) {
        const int idx = jj + ehalf;
        const bool valid = idx < deg;              // odd-deg tail guard
        const int s = bp[min(idx, deg - 1)];       // clamped: stays in this bin
        float e = el[(s << 2) + head] + er_h;
        e = e > 0.f ? e : NEG_SLOPE * e;
        float ex = __expf(e);
        ex = valid ? ex : 0.f;
        sm += ex;
        uint4 pv = hp[(size_t)s * 32];
        acc[0] = fmaf(ex, bf_lo(pv.x), acc[0]);
        acc[1] = fmaf(ex, bf_hi(pv.x), acc[1]);
        acc[2] = fmaf(ex, bf_lo(pv.y), acc[2]);
        acc[3] = fmaf(ex, bf_hi(pv.y), acc[3]);
        acc[4] = fmaf(ex, bf_lo(pv.z), acc[4]);
        acc[5] = fmaf(ex, bf_hi(pv.z), acc[5]);
        acc[6] = fmaf(ex, bf_lo(pv.w), acc[6]);
        acc[7] = fmaf(ex, bf_hi(pv.w), acc[7]);
    }

    // combine edge-halves (lane l and l^32 hold the same features/head)
    #pragma unroll
    for (int i = 0; i < 8; ++i) acc[i] += __shfl_xor(acc[i], 32);
    sm += __shfl_xor(sm, 32);

    const float inv = (deg > 0) ? 1.f / sm : 0.f;
    if (ehalf == 0) {
        uint4 r;
        r.x = (unsigned)f2bf(fmaxf(acc[0]*inv, 0.f)) | ((unsigned)f2bf(fmaxf(acc[1]*inv, 0.f)) << 16);
        r.y = (unsigned)f2bf(fmaxf(acc[2]*inv, 0.f)) | ((unsigned)f2bf(fmaxf(acc[3]*inv, 0.f)) << 16);
        r.z = (unsigned)f2bf(fmaxf(acc[4]*inv, 0.f)) | ((unsigned)f2bf(fmaxf(acc[5]*inv, 0.f)) << 16);
        r.w = (unsigned)f2bf(fmaxf(acc[6]*inv, 0.f)) | ((unsigned)f2bf(fmaxf(acc[7]*inv, 0.f)) << 16);
        aggb4[(d << 5) + hlane] = r;
    }
}

// ---------------------------------------------------------------------------
extern "C" void kernel_launch(void* const* d_in, const int* in_sizes, int n_in,
                              void* d_out, int out_size, void* d_ws, size_t ws_size,
                              hipStream_t stream)
{
    const float* features = (const float*)d_in[0];
    const float* W0       = (const float*)d_in[1];
    const float* attn_l   = (const float*)d_in[2];
    const float* attn_r   = (const float*)d_in[3];
    const float* fc_W     = (const float*)d_in[4];
    const float* fc_b     = (const float*)d_in[5];
    const int*   src      = (const int*)d_in[6];
    const int*   dst      = (const int*)d_in[7];
    float* out = (float*)d_out;

    char* ws = (char*)d_ws;
    unsigned short* hb16 = (unsigned short*)ws;                 // N*256 bf16
    ws += (size_t)N_NODES * NFEAT * sizeof(unsigned short);
    unsigned short* aggb = (unsigned short*)ws;                 // N*256 bf16
    ws += (size_t)N_NODES * NFEAT * sizeof(unsigned short);
    unsigned short* Wf = (unsigned short*)ws;                   // 256*256 bf16
    ws += (size_t)IN_DIM * NFEAT * sizeof(unsigned short);
    unsigned short* Wf2 = (unsigned short*)ws;                  // 8*48*32 bf16
    ws += (size_t)8 * NC_PAD * 32 * sizeof(unsigned short);
    float* el = (float*)ws;  ws += (size_t)N_NODES * HEADS * sizeof(float);
    float* er = (float*)ws;  ws += (size_t)N_NODES * HEADS * sizeof(float);
    int* cnt = (int*)ws;     ws += (size_t)N_NODES * sizeof(int);
    int* bins_src = (int*)ws;                                   // N*64*4 B

    // 0) weight packs + cnt zeroing (one dispatch)
    pack_weights<<<(65536 + 8 * NC_PAD * 32 + 255) / 256, 256, 0, stream>>>(
        W0, Wf, fc_W, Wf2, cnt);

    // 1) projection (MFMA, direct A-frags) + fused el/er + bf16 h
    proj_mfma<<<(N_NODES + 63) / 64, 256, 0, stream>>>(
        features, Wf, attn_l, attn_r, hb16, el, er);

    // 2) slim binned scatter (4 B per edge)
    scatter_bins<<<(N_EDGES + 255) / 256, 256, 0, stream>>>(
        src, dst, cnt, bins_src);

    // 3) fused aggregation with inline logits
    gat_agg_kernel<<<(N_NODES + 3) / 4, 256, 0, stream>>>(
        cnt, bins_src, el, er, (const uint4*)hb16, (uint4*)aggb);

    // 4) final FC (MFMA)
    fc_mfma<<<(N_NODES + 63) / 64, 256, 0, stream>>>(aggb, Wf2, fc_b, out);
}

// Round 11
// 154.832 us; speedup vs baseline: 1.1347x; 1.1347x over previous
//
#include <hip/hip_runtime.h>

#define N_NODES 50000
#define N_EDGES 800000
#define IN_DIM 256
#define HID 64
#define HEADS 4
#define NFEAT 256   /* HEADS*HID */
#define N_CLASSES 40
#define NC_PAD 48
#define NEG_SLOPE 0.2f
#define BIN_CAP 64  /* max in-degree; Poisson(16) -> P(>=64) ~ 1e-18 */

typedef __attribute__((ext_vector_type(8))) short short8;
typedef __attribute__((ext_vector_type(4))) float f32x4;

__device__ __forceinline__ unsigned short f2bf(float x) {
    unsigned u = __float_as_uint(x);
    unsigned r = u + 0x7FFFu + ((u >> 16) & 1u);   // round-to-nearest-even
    return (unsigned short)(r >> 16);
}
__device__ __forceinline__ float bf_lo(unsigned u) {
    return __uint_as_float(u << 16);
}
__device__ __forceinline__ float bf_hi(unsigned u) {
    return __uint_as_float(u & 0xFFFF0000u);
}

// ---------------------------------------------------------------------------
// Pack W0 [256][256] and fc_W [256][40->48] into MFMA B-frag bf16 layouts.
// Also zeroes cnt[] (replaces a memset dispatch).
__global__ __launch_bounds__(256) void pack_weights(
    const float* __restrict__ W0, unsigned short* __restrict__ Wf,
    const float* __restrict__ W2, unsigned short* __restrict__ Wf2,
    int* __restrict__ cnt)
{
    int t = blockIdx.x * 256 + threadIdx.x;
    if (t < N_NODES) cnt[t] = 0;
    if (t < 65536) {
        int c = t & 255;
        int k = t >> 8;
        int kb = k >> 5, r = k & 31;
        int g = r >> 3, e = r & 7;
        Wf[((size_t)(kb * 256 + c) * 4 + g) * 8 + e] = f2bf(W0[(size_t)k * 256 + c]);
    } else {
        int t2 = t - 65536;
        if (t2 >= 8 * NC_PAD * 32) return;
        int c = (t2 >> 5) % NC_PAD;
        int kb = t2 / (NC_PAD * 32);
        int r = t2 & 31;
        int g = r >> 3, e = r & 7;
        int k = kb * 32 + g * 8 + e;
        float v = (c < N_CLASSES) ? W2[(size_t)k * N_CLASSES + c] : 0.f;
        Wf2[((size_t)(kb * NC_PAD + c) * 4 + g) * 8 + e] = f2bf(v);
    }
}

// ---------------------------------------------------------------------------
// Projection via MFMA bf16, direct-register A-frags (no LDS, no barriers),
// fused el/er epilogue, bf16 h output.
__global__ __launch_bounds__(256) void proj_mfma(
    const float* __restrict__ feat, const unsigned short* __restrict__ Wf,
    const float* __restrict__ al, const float* __restrict__ ar,
    unsigned short* __restrict__ hb16, float* __restrict__ el, float* __restrict__ er)
{
    const int tid  = threadIdx.x;
    const int lane = tid & 63;
    const int w    = tid >> 6;
    const int c    = lane & 15;
    const int g    = lane >> 4;
    const int row0 = blockIdx.x * 64;

    float alv[16], arv[16];
    #pragma unroll
    for (int f = 0; f < 16; ++f) { alv[f] = al[f * 16 + c]; arv[f] = ar[f * 16 + c]; }

    f32x4 acc[16];
    #pragma unroll
    for (int f = 0; f < 16; ++f) acc[f] = (f32x4){0.f, 0.f, 0.f, 0.f};

    const int arow = min(row0 + w * 16 + c, N_NODES - 1);
    const float* ap = &feat[(size_t)arow * IN_DIM + g * 8];

    for (int kb = 0; kb < 8; ++kb) {
        float4 v0 = *reinterpret_cast<const float4*>(ap + kb * 32);
        float4 v1 = *reinterpret_cast<const float4*>(ap + kb * 32 + 4);
        unsigned short us[8];
        us[0]=f2bf(v0.x); us[1]=f2bf(v0.y); us[2]=f2bf(v0.z); us[3]=f2bf(v0.w);
        us[4]=f2bf(v1.x); us[5]=f2bf(v1.y); us[6]=f2bf(v1.z); us[7]=f2bf(v1.w);
        short8 av = *reinterpret_cast<short8*>(us);
        #pragma unroll
        for (int f = 0; f < 16; ++f) {
            short8 bv = *reinterpret_cast<const short8*>(
                &Wf[((size_t)(kb * 256 + f * 16 + c) * 4 + g) * 8]);
            acc[f] = __builtin_amdgcn_mfma_f32_16x16x32_bf16(av, bv, acc[f], 0, 0, 0);
        }
    }

    const int baserow = row0 + w * 16 + g * 4;
    #pragma unroll
    for (int reg = 0; reg < 4; ++reg) {
        int grow = baserow + reg;
        bool ok = grow < N_NODES;
        float pl[4] = {0.f,0.f,0.f,0.f}, pr[4] = {0.f,0.f,0.f,0.f};
        #pragma unroll
        for (int f = 0; f < 16; ++f) {
            float v = acc[f][reg];
            pl[f >> 2] += v * alv[f];
            pr[f >> 2] += v * arv[f];
            if (ok) hb16[(size_t)grow * NFEAT + f * 16 + c] = f2bf(v);
        }
        #pragma unroll
        for (int hh = 0; hh < 4; ++hh) {
            #pragma unroll
            for (int off = 8; off; off >>= 1) {
                pl[hh] += __shfl_xor(pl[hh], off);
                pr[hh] += __shfl_xor(pr[hh], off);
            }
        }
        if (ok && c == 0) {
            #pragma unroll
            for (int hh = 0; hh < 4; ++hh) {
                el[grow * 4 + hh] = pl[hh];
                er[grow * 4 + hh] = pr[hh];
            }
        }
    }
}

// ---------------------------------------------------------------------------
// Binned scatter: builds per-dst edge lists AND the edge exp-logits.
// Bin entry = {src, bf16(ex0)|bf16(ex1)<<16, bf16(ex2)|bf16(ex3)<<16, 0}.
__global__ __launch_bounds__(256) void scatter_bins(
    const int* __restrict__ src, const int* __restrict__ dst,
    int* __restrict__ cnt,
    const float4* __restrict__ el4, const float4* __restrict__ er4,
    uint4* __restrict__ bins)
{
    int e = blockIdx.x * 256 + threadIdx.x;
    if (e >= N_EDGES) return;
    int d = dst[e], s = src[e];
    int pos = atomicAdd(&cnt[d], 1);
    if (pos >= BIN_CAP) return;   // impossible for this input (P ~ 1e-18)
    float4 l = el4[s];
    float4 r = er4[d];
    float t0 = l.x + r.x; t0 = t0 > 0.f ? t0 : NEG_SLOPE * t0;
    float t1 = l.y + r.y; t1 = t1 > 0.f ? t1 : NEG_SLOPE * t1;
    float t2 = l.z + r.z; t2 = t2 > 0.f ? t2 : NEG_SLOPE * t2;
    float t3 = l.w + r.w; t3 = t3 > 0.f ? t3 : NEG_SLOPE * t3;
    unsigned y = (unsigned)f2bf(__expf(t0)) | ((unsigned)f2bf(__expf(t1)) << 16);
    unsigned z = (unsigned)f2bf(__expf(t2)) | ((unsigned)f2bf(__expf(t3)) << 16);
    bins[(d << 6) + pos] = make_uint4((unsigned)s, y, z, 0u);
}

// ---------------------------------------------------------------------------
// Fused aggregation + FC. Block = 16 nodes (4 per wave; 50000 = 3125*16,
// no partial blocks -> barrier-safe). Phase 1 per node: r9's gather loop
// (one wave per node, direct half-wave-uniform entry loads, deferred
// normalization); normalized relu'd bf16 row -> LDS. Phase 2 after one
// barrier: waves 0-2 each compute one 16-col MFMA frag of
// out = lds_agg @ fc_W + b, writing f32 output directly (no aggb round-trip).
__global__ __launch_bounds__(256) void gat_agg_fc_kernel(
    const int* __restrict__ cnt, const uint4* __restrict__ bins,
    const uint4* __restrict__ hb4, const unsigned short* __restrict__ Wf2,
    const float* __restrict__ bias, float* __restrict__ out)
{
    __shared__ unsigned short lds_agg[16][264];   // 528B row stride: 16B-aligned, 2-way-bank-safe
    const int lane  = threadIdx.x & 63;
    const int w     = threadIdx.x >> 6;
    const int hlane = lane & 31;
    const int head  = hlane >> 3;
    const int ehalf = lane >> 5;
    const bool hi   = (head & 1) != 0;
    const int nbase = blockIdx.x * 16;

    // ---- phase 1: per-node aggregation (4 nodes per wave) ----
    for (int t = 0; t < 4; ++t) {
        const int d   = nbase + w * 4 + t;
        const int deg = min(cnt[d], BIN_CAP);

        float acc[8] = {0.f,0.f,0.f,0.f,0.f,0.f,0.f,0.f};
        float sm = 0.f;
        const uint4* hp = hb4 + hlane;
        const uint4* bp = bins + (d << 6);

        #pragma unroll 4
        for (int jj = 0; jj < deg; jj += 2) {
            const int idx = jj + ehalf;
            const bool valid = idx < deg;              // odd-deg tail guard
            uint4 entry = bp[min(idx, deg - 1)];       // clamped: stays in this bin
            unsigned ew = (head & 2) ? entry.z : entry.y;
            float ex = hi ? bf_hi(ew) : bf_lo(ew);
            ex = valid ? ex : 0.f;
            sm += ex;
            uint4 pv = hp[(size_t)entry.x * 32];
            acc[0] = fmaf(ex, bf_lo(pv.x), acc[0]);
            acc[1] = fmaf(ex, bf_hi(pv.x), acc[1]);
            acc[2] = fmaf(ex, bf_lo(pv.y), acc[2]);
            acc[3] = fmaf(ex, bf_hi(pv.y), acc[3]);
            acc[4] = fmaf(ex, bf_lo(pv.z), acc[4]);
            acc[5] = fmaf(ex, bf_hi(pv.z), acc[5]);
            acc[6] = fmaf(ex, bf_lo(pv.w), acc[6]);
            acc[7] = fmaf(ex, bf_hi(pv.w), acc[7]);
        }

        // combine edge-halves (lane l and l^32 hold the same features/head)
        #pragma unroll
        for (int i = 0; i < 8; ++i) acc[i] += __shfl_xor(acc[i], 32);
        sm += __shfl_xor(sm, 32);

        const float inv = (deg > 0) ? 1.f / sm : 0.f;
        if (ehalf == 0) {
            unsigned short us[8];
            #pragma unroll
            for (int i = 0; i < 8; ++i) us[i] = f2bf(fmaxf(acc[i] * inv, 0.f));
            *reinterpret_cast<uint4*>(&lds_agg[w * 4 + t][hlane * 8]) =
                *reinterpret_cast<uint4*>(us);
        }
    }

    __syncthreads();

    // ---- phase 2: FC via MFMA on the 16x256 LDS tile ----
    if (w < 3) {
        const int c = lane & 15;
        const int g = lane >> 4;
        f32x4 facc = (f32x4){0.f, 0.f, 0.f, 0.f};
        #pragma unroll
        for (int kb = 0; kb < 8; ++kb) {
            short8 av = *reinterpret_cast<const short8*>(&lds_agg[c][kb * 32 + g * 8]);
            short8 bv = *reinterpret_cast<const short8*>(
                &Wf2[((size_t)(kb * NC_PAD + w * 16 + c) * 4 + g) * 8]);
            facc = __builtin_amdgcn_mfma_f32_16x16x32_bf16(av, bv, facc, 0, 0, 0);
        }
        const int col = w * 16 + c;
        if (col < N_CLASSES) {
            const float b = bias[col];
            #pragma unroll
            for (int reg = 0; reg < 4; ++reg) {
                out[(size_t)(nbase + g * 4 + reg) * N_CLASSES + col] = facc[reg] + b;
            }
        }
    }
}

// ---------------------------------------------------------------------------
extern "C" void kernel_launch(void* const* d_in, const int* in_sizes, int n_in,
                              void* d_out, int out_size, void* d_ws, size_t ws_size,
                              hipStream_t stream)
{
    const float* features = (const float*)d_in[0];
    const float* W0       = (const float*)d_in[1];
    const float* attn_l   = (const float*)d_in[2];
    const float* attn_r   = (const float*)d_in[3];
    const float* fc_W     = (const float*)d_in[4];
    const float* fc_b     = (const float*)d_in[5];
    const int*   src      = (const int*)d_in[6];
    const int*   dst      = (const int*)d_in[7];
    float* out = (float*)d_out;

    char* ws = (char*)d_ws;
    unsigned short* hb16 = (unsigned short*)ws;                 // N*256 bf16
    ws += (size_t)N_NODES * NFEAT * sizeof(unsigned short);
    unsigned short* Wf = (unsigned short*)ws;                   // 256*256 bf16
    ws += (size_t)IN_DIM * NFEAT * sizeof(unsigned short);
    unsigned short* Wf2 = (unsigned short*)ws;                  // 8*48*32 bf16
    ws += (size_t)8 * NC_PAD * 32 * sizeof(unsigned short);
    float* el = (float*)ws;  ws += (size_t)N_NODES * HEADS * sizeof(float);
    float* er = (float*)ws;  ws += (size_t)N_NODES * HEADS * sizeof(float);
    int* cnt = (int*)ws;     ws += (size_t)N_NODES * sizeof(int);
    ws += (16 - ((size_t)ws & 15)) & 15;                        // 16B align
    uint4* bins = (uint4*)ws;                                   // N*64*16 B

    // 0) weight packs + cnt zeroing (one dispatch)
    pack_weights<<<(65536 + 8 * NC_PAD * 32 + 255) / 256, 256, 0, stream>>>(
        W0, Wf, fc_W, Wf2, cnt);

    // 1) projection (MFMA, direct A-frags) + fused el/er + bf16 h
    proj_mfma<<<(N_NODES + 63) / 64, 256, 0, stream>>>(
        features, Wf, attn_l, attn_r, hb16, el, er);

    // 2) binned scatter with fused edge-exp
    scatter_bins<<<(N_EDGES + 255) / 256, 256, 0, stream>>>(
        src, dst, cnt, (const float4*)el, (const float4*)er, bins);

    // 3) fused aggregation + FC (16 nodes per block; no aggb round-trip)
    gat_agg_fc_kernel<<<N_NODES / 16, 256, 0, stream>>>(
        cnt, bins, (const uint4*)hb16, Wf2, fc_b, out);
}